// Round 3
// baseline (1262.816 us; speedup 1.0000x reference)
//
#include <hip/hip_runtime.h>
#include <stdint.h>
#include <stddef.h>
#include <math.h>

// WindowAttention MI355X (gfx950). B=16 C=512 H=W=64 WS=16 HEADS=8 d=64.
// L=256 windows, N=256 positions, attention batches (n,h)=2048 of 256x256,d=64.
//
// R2 (resubmit; prior round never ran — GPU acquisition timeout):
//  latency-stall fix for the GEMMs (qkv was 240us @ MfmaUtil 18%, occ 22%):
//  - weights PACKED into fragment order (w1p[t][ks][lane][8]) by the cvt
//    kernel -> each wave weight-load is one dense contiguous 1KB fetch.
//  - 512-thr blocks, 64-row A-tile (LDS 64KB) -> 2 blocks/CU x 8 waves
//    = 16 waves/CU (4/SIMD) for TLP latency hiding. __launch_bounds__(512,4).
//  - 8 waves x 64 couts: qkv nc-chunks of 512 = exactly q/k/v, head==wave.
//  - qkv epilogue: direct scalar bf16 stores (no LDS transpose) - frees LDS;
//    adjacent ct tiles complete 64B lines in L2.
//
// Workspace: q[n][h][l][d] 67MB (o overwrites in-place) | k 67MB | v 67MB |
//            w1p bf16 1.5MB | w2p bf16 0.5MB.  Total ~203 MB.

typedef __bf16 bf16;
typedef __attribute__((ext_vector_type(8))) __bf16 bf16x8;
typedef __attribute__((ext_vector_type(4))) __bf16 bf16x4;
typedef __attribute__((ext_vector_type(4))) float f32x4;

#define MFMA16(A, B, C) __builtin_amdgcn_mfma_f32_16x16x32_bf16((A), (B), (C), 0, 0, 0)

__device__ __forceinline__ float fast_exp2(float x) { return __builtin_amdgcn_exp2f(x); }

// XOR-swizzled A-tile element index: rows x 512 cols bf16, unpadded.
// granule (16B) index = (c>>3) ^ (n>>4 & 7) ^ (n & 7): spreads both the
// n-strided staging writes and the b128 frag reads.
__device__ __forceinline__ int aswz(int n, int c) {
  int g = (c >> 3) ^ ((n >> 4) & 7) ^ (n & 7);
  return n * 512 + (g << 3) + (c & 7);
}

// ---------------------------------------------------------------- cvt + pack
// Pack weights into per-wave fragment order:
//   wp[((t*16 + ks)*64 + lane)*8 + e] = wf[t*16 + (lane&15)][ks*32 + (lane>>4)*8 + e]
// so a wave's (tile t, kslice ks) load is one contiguous 1KB block.
// w1: 96 tiles (1536 couts), w2: 32 tiles (512 couts). 1 thread per (t,ks,lane).
__global__ void cvt_pack(const float* __restrict__ w1f, const float* __restrict__ w2f,
                         bf16* __restrict__ w1p, bf16* __restrict__ w2p) {
  int i = blockIdx.x * 256 + threadIdx.x;   // 0..131071
  const float* src;
  bf16* dst;
  if (i < 98304) { src = w1f; dst = w1p; }
  else           { src = w2f; dst = w2p; i -= 98304; }
  int lane = i & 63;
  int ks   = (i >> 6) & 15;
  int t    = i >> 10;
  int cout = t * 16 + (lane & 15);
  int c0   = ks * 32 + (lane >> 4) * 8;
  float4 a = *(const float4*)(src + (size_t)cout * 512 + c0);
  float4 b = *(const float4*)(src + (size_t)cout * 512 + c0 + 4);
  bf16x8 r;
  r[0] = (bf16)a.x; r[1] = (bf16)a.y; r[2] = (bf16)a.z; r[3] = (bf16)a.w;
  r[4] = (bf16)b.x; r[5] = (bf16)b.y; r[6] = (bf16)b.z; r[7] = (bf16)b.w;
  *(bf16x8*)(dst + (size_t)i * 8) = r;
}

// ---------------------------------------------------------------- QKV GEMM
// Block = 64 rows (window l, n-quarter) x K=512, A swizzled in 64KB LDS.
// 8 waves x 64 couts; 3 chunks of 512 couts = {q,k,v}; head hh == wave.
// Per wave per ks: 4 packed 1KB weight loads + 4 ds_read_b128 + 16 MFMA.
// 2 blocks/CU, 16 waves/CU: TLP hides L2/L3 weight latency.
__global__ void __launch_bounds__(512, 4) gemm_qkv(
    const float* __restrict__ x, const bf16* __restrict__ w1p,
    const float* __restrict__ b1,
    bf16* __restrict__ qo, bf16* __restrict__ ko, bf16* __restrict__ vo) {
  extern __shared__ bf16 Al[];              // 64*512 swizzled
  const int tid = threadIdx.x;
  const int bm  = blockIdx.x;               // 0..1023
  const int l   = bm >> 2;
  const int n0  = (bm & 3) << 6;
  const int b   = l >> 4, ih = (l >> 2) & 3, iw = l & 3;
  const int h0  = ih * 16 + (n0 >> 4);      // 4 h-rows of the window
  const int w0  = iw * 16;

  // stage A: 64 n-rows x 512 c, fp32 gather -> bf16 swizzled LDS
  for (int j = 0; j < 16; ++j) {
    int f4  = j * 512 + tid;                // 0..8191
    int c   = f4 >> 4;                      // 16 float4 per channel
    int qq  = f4 & 15;
    int wsh = qq >> 2;                      // 0..3
    int w4  = (qq & 3) << 2;
    float4 xf = *(const float4*)(x + (((b * 512 + c) * 64 + h0 + wsh) * 64 + w0 + w4));
    int nb = wsh * 16 + w4;                 // 0..60
    Al[aswz(nb + 0, c)] = (bf16)xf.x;
    Al[aswz(nb + 1, c)] = (bf16)xf.y;
    Al[aswz(nb + 2, c)] = (bf16)xf.z;
    Al[aswz(nb + 3, c)] = (bf16)xf.w;
  }
  __syncthreads();

  const int wave = tid >> 6, lane = tid & 63;
  const int l15 = lane & 15, quad = lane >> 4;
  const f32x4 fz = {0.f, 0.f, 0.f, 0.f};

  for (int nc = 0; nc < 3; ++nc) {
    const int t0w = nc * 512 + wave * 64;   // cout base of this wave's chunk
    const int tb  = t0w >> 4;               // base 16-cout tile
    f32x4 acc[4][4];
#pragma unroll
    for (int a = 0; a < 4; ++a)
#pragma unroll
      for (int c2 = 0; c2 < 4; ++c2) acc[a][c2] = fz;

#pragma unroll
    for (int ks = 0; ks < 16; ++ks) {
      bf16x8 bfr[4];
#pragma unroll
      for (int ct = 0; ct < 4; ++ct)
        bfr[ct] = *(const bf16x8*)&w1p[((size_t)((tb + ct) * 16 + ks) * 64 + lane) * 8];
      bf16x8 af[4];
#pragma unroll
      for (int lt = 0; lt < 4; ++lt)
        af[lt] = *(const bf16x8*)&Al[aswz(lt * 16 + l15, ks * 32 + quad * 8)];
#pragma unroll
      for (int lt = 0; lt < 4; ++lt)
#pragma unroll
        for (int ct = 0; ct < 4; ++ct)
          acc[lt][ct] = MFMA16(af[lt], bfr[ct], acc[lt][ct]);
    }

    // epilogue: direct scalar bf16 stores. C-frag: col(=cout)=l15, row(=n)=quad*4+r.
    bf16* dst = (nc == 0) ? qo : (nc == 1) ? ko : vo;
    const float scale = (nc == 0) ? 0.125f : 1.0f;
    const int hh = wave;                    // head index
    float bias[4];
#pragma unroll
    for (int ct = 0; ct < 4; ++ct) bias[ct] = b1[t0w + ct * 16 + l15];

#pragma unroll
    for (int lt = 0; lt < 4; ++lt)
#pragma unroll
      for (int ct = 0; ct < 4; ++ct)
#pragma unroll
        for (int r = 0; r < 4; ++r) {
          int n = n0 + lt * 16 + quad * 4 + r;
          dst[((size_t)(n * 8 + hh) * 256 + l) * 64 + ct * 16 + l15] =
              (bf16)((acc[lt][ct][r] + bias[ct]) * scale);
        }
  }
}

// ---------------------------------------------------------------- attention
// One block per (n,h). K LDS [256][72], V^T LDS [64][264], per-wave P [16][264].
// Output overwrites q in-place; writes via per-wave transpose -> 128B chunks.
__global__ void __launch_bounds__(512, 2) attn_win(
    bf16* __restrict__ qio, const bf16* __restrict__ kg, const bf16* __restrict__ vg) {
  extern __shared__ bf16 sm[];
  bf16* Kl = sm;
  bf16* Vt = sm + 256 * 72;
  bf16* Pl = Vt + 64 * 264;
  const int tid = threadIdx.x;
  const int bb = blockIdx.x;
  const int n = bb >> 3, h = bb & 7;
  const size_t base = (size_t)(n * 8 + h) * 16384;
  const bf16* Kg = kg + base;
  const bf16* Vg = vg + base;
  bf16* Qg = qio + base;

  for (int j = 0; j < 4; ++j) {
    int cc = j * 512 + tid;
    int m = cc >> 3, dc = cc & 7;
    bf16x8 t = *(const bf16x8*)(Kg + m * 64 + dc * 8);
    *(bf16x8*)&Kl[m * 72 + dc * 8] = t;
  }
  for (int j = 0; j < 4; ++j) {
    int cc = j * 512 + tid;
    int dc = cc >> 8, m = cc & 255;
    bf16x8 t = *(const bf16x8*)(Vg + m * 64 + dc * 8);
#pragma unroll
    for (int s = 0; s < 8; ++s) Vt[(dc * 8 + s) * 264 + m] = t[s];
  }

  const int wave = tid >> 6, lane = tid & 63;
  const int l15 = lane & 15, quad = lane >> 4;
  const int lb = wave * 32;
  bf16* Pw = Pl + wave * 16 * 264;

  bf16x8 qf[2][2];
#pragma unroll
  for (int lt = 0; lt < 2; ++lt)
#pragma unroll
    for (int ks = 0; ks < 2; ++ks)
      qf[lt][ks] = *(const bf16x8*)(Qg + (lb + lt * 16 + l15) * 64 + ks * 32 + quad * 8);

  __syncthreads();

  const f32x4 fz = {0.f, 0.f, 0.f, 0.f};
  const float LOG2E = 1.44269504088896340736f;
  for (int lt = 0; lt < 2; ++lt) {
    f32x4 s[16];
#pragma unroll
    for (int mt = 0; mt < 16; ++mt) s[mt] = fz;
#pragma unroll
    for (int mt = 0; mt < 16; ++mt)
#pragma unroll
      for (int ks = 0; ks < 2; ++ks) {
        bf16x8 kf = *(const bf16x8*)&Kl[(mt * 16 + l15) * 72 + ks * 32 + quad * 8];
        s[mt] = MFMA16(qf[lt][ks], kf, s[mt]);
      }
    float rmax[4], rsum[4];
#pragma unroll
    for (int r = 0; r < 4; ++r) {
      float mx = s[0][r];
#pragma unroll
      for (int mt = 1; mt < 16; ++mt) mx = fmaxf(mx, s[mt][r]);
#pragma unroll
      for (int xo = 1; xo < 16; xo <<= 1) mx = fmaxf(mx, __shfl_xor(mx, xo, 16));
      rmax[r] = mx;
      rsum[r] = 0.f;
    }
#pragma unroll
    for (int mt = 0; mt < 16; ++mt) {
#pragma unroll
      for (int r = 0; r < 4; ++r) {
        float p = fast_exp2((s[mt][r] - rmax[r]) * LOG2E);
        bf16 pb = (bf16)p;
        rsum[r] += (float)pb;
        Pw[(quad * 4 + r) * 264 + mt * 16 + l15] = pb;
      }
    }
#pragma unroll
    for (int r = 0; r < 4; ++r)
#pragma unroll
      for (int xo = 1; xo < 16; xo <<= 1) rsum[r] += __shfl_xor(rsum[r], xo, 16);

    bf16x8 pf[8];
#pragma unroll
    for (int mk = 0; mk < 8; ++mk)
      pf[mk] = *(const bf16x8*)&Pw[l15 * 264 + mk * 32 + quad * 8];
    f32x4 of[4];
#pragma unroll
    for (int dt = 0; dt < 4; ++dt) of[dt] = fz;
#pragma unroll
    for (int dt = 0; dt < 4; ++dt)
#pragma unroll
      for (int mk = 0; mk < 8; ++mk) {
        bf16x8 vf = *(const bf16x8*)&Vt[(dt * 16 + l15) * 264 + mk * 32 + quad * 8];
        of[dt] = MFMA16(pf[mk], vf, of[dt]);
      }
    float inv[4];
#pragma unroll
    for (int r = 0; r < 4; ++r) inv[r] = 1.0f / rsum[r];

    // o-write: per-wave transpose (reuse Pw) -> 128B contiguous bf16x8 stores
    bf16* Ew = Pw;  // [16][72] region
#pragma unroll
    for (int dt = 0; dt < 4; ++dt)
#pragma unroll
      for (int r = 0; r < 4; ++r)
        Ew[(quad * 4 + r) * 72 + dt * 16 + l15] = (bf16)(of[dt][r] * inv[r]);
    const int rr = lane >> 3, ch8 = (lane & 7) * 8;
#pragma unroll
    for (int half = 0; half < 2; ++half) {
      int row = half * 8 + rr;
      bf16x8 vv = *(const bf16x8*)&Ew[row * 72 + ch8];
      *(bf16x8*)(Qg + (lb + lt * 16 + row) * 64 + ch8) = vv;
    }
  }
}

// ---------------------------------------------------------------- out proj
// Swapped MFMA operands: D = W2 x O^T, C-layout row=cout col=n, so stores are
// 64B-contiguous fp32 along w. 512-thr blocks, 8 waves x 64 couts = all 512.
__global__ void __launch_bounds__(512, 4) gemm_out(
    const bf16* __restrict__ og, const bf16* __restrict__ w2p,
    const float* __restrict__ b2, float* __restrict__ out) {
  extern __shared__ bf16 Al[];  // 64*512 swizzled
  const int tid = threadIdx.x;
  const int bm = blockIdx.x;    // 0..1023
  const int l = bm >> 2;
  const int n0 = (bm & 3) << 6;
  const int b = l >> 4, ih = (l >> 2) & 3, iw = l & 3;

  for (int j = 0; j < 8; ++j) {  // o[n][h][l][d] gather -> swizzled LDS rows
    int cc = j * 512 + tid;      // 0..4095
    int nl = cc >> 6;            // 0..63
    int ch = cc & 63;
    int hh = ch >> 3, d8 = (ch & 7) * 8;
    bf16x8 t = *(const bf16x8*)(og + ((size_t)((n0 + nl) * 8 + hh) * 256 + l) * 64 + d8);
    *(bf16x8*)&Al[aswz(nl, ch * 8)] = t;
  }
  __syncthreads();

  const int wave = tid >> 6, lane = tid & 63;
  const int l15 = lane & 15, quad = lane >> 4;
  const int t0w = wave * 64;     // this wave's 64 couts (512 total)
  const int tb  = wave * 4;
  const f32x4 fz = {0.f, 0.f, 0.f, 0.f};

  f32x4 acc[4][4];
#pragma unroll
  for (int a = 0; a < 4; ++a)
#pragma unroll
    for (int c2 = 0; c2 < 4; ++c2) acc[a][c2] = fz;

#pragma unroll
  for (int ks = 0; ks < 16; ++ks) {
    bf16x8 bfr[4];
#pragma unroll
    for (int ct = 0; ct < 4; ++ct)
      bfr[ct] = *(const bf16x8*)&w2p[((size_t)((tb + ct) * 16 + ks) * 64 + lane) * 8];
    bf16x8 af[4];
#pragma unroll
    for (int lt = 0; lt < 4; ++lt)
      af[lt] = *(const bf16x8*)&Al[aswz(lt * 16 + l15, ks * 32 + quad * 8)];
#pragma unroll
    for (int lt = 0; lt < 4; ++lt)
#pragma unroll
      for (int ct = 0; ct < 4; ++ct)
        acc[lt][ct] = MFMA16(bfr[ct], af[lt], acc[lt][ct]);  // swapped: rows=cout
  }

#pragma unroll
  for (int ct = 0; ct < 4; ++ct) {
    float4 bias4 = *(const float4*)&b2[t0w + ct * 16 + quad * 4];
#pragma unroll
    for (int lt = 0; lt < 4; ++lt) {
      const int nbase = n0 + lt * 16;       // mult of 16 -> wsh uniform
      const int wsh = nbase >> 4;
      size_t rowbase = (((size_t)b * 512) * 64 + (size_t)ih * 16 + wsh) * 64 + iw * 16 + l15;
#pragma unroll
      for (int r = 0; r < 4; ++r) {
        int cout = t0w + ct * 16 + quad * 4 + r;
        out[rowbase + (size_t)cout * 4096] = acc[lt][ct][r] + ((const float*)&bias4)[r];
      }
    }
  }
}

// ---------------------------------------------------------------- launch
extern "C" void kernel_launch(void* const* d_in, const int* in_sizes, int n_in,
                              void* d_out, int out_size, void* d_ws, size_t ws_size,
                              hipStream_t stream) {
  (void)in_sizes; (void)n_in; (void)out_size; (void)ws_size;
  const float* x   = (const float*)d_in[0];
  const float* w1f = (const float*)d_in[1];
  const float* b1  = (const float*)d_in[2];
  const float* w2f = (const float*)d_in[3];
  const float* b2  = (const float*)d_in[4];
  float* out = (float*)d_out;

  char* ws = (char*)d_ws;
  bf16* q   = (bf16*)(ws);
  bf16* k   = (bf16*)(ws + 67108864ull);
  bf16* v   = (bf16*)(ws + 134217728ull);
  bf16* w1p = (bf16*)(ws + 201326592ull);
  bf16* w2p = (bf16*)(ws + 201326592ull + 1572864ull);

  const int LDS_QKV  = 64 * 512 * 2;                              //  65,536 B
  const int LDS_ATTN = (256 * 72 + 64 * 264 + 8 * 16 * 264) * 2;  // 138,240 B
  const int LDS_OUT  = 64 * 512 * 2;                              //  65,536 B
  hipFuncSetAttribute(reinterpret_cast<const void*>(gemm_qkv),
                      hipFuncAttributeMaxDynamicSharedMemorySize, LDS_QKV);
  hipFuncSetAttribute(reinterpret_cast<const void*>(attn_win),
                      hipFuncAttributeMaxDynamicSharedMemorySize, LDS_ATTN);
  hipFuncSetAttribute(reinterpret_cast<const void*>(gemm_out),
                      hipFuncAttributeMaxDynamicSharedMemorySize, LDS_OUT);

  hipLaunchKernelGGL(cvt_pack, dim3(512), dim3(256), 0, stream, w1f, w2f, w1p, w2p);
  hipLaunchKernelGGL(gemm_qkv, dim3(1024), dim3(512), LDS_QKV, stream, x, w1p, b1, q, k, v);
  hipLaunchKernelGGL(attn_win, dim3(2048), dim3(512), LDS_ATTN, stream, q, k, v);
  hipLaunchKernelGGL(gemm_out, dim3(1024), dim3(512), LDS_OUT, stream, q, w2p, b2, out);
}

// Round 7
// 979.674 us; speedup vs baseline: 1.2890x; 1.2890x over previous
//
#include <hip/hip_runtime.h>
#include <stdint.h>
#include <stddef.h>
#include <math.h>

// WindowAttention MI355X (gfx950). B=16 C=512 H=W=64 WS=16 HEADS=8 d=64.
// L=256 windows, N=256 positions, attention batches (n,h)=2048 of 256x256,d=64.
//
// R3 (4th submit; prior rounds never ran — GPU acquisition timeouts):
//     fix R2's write-amplification regression (qkv 920us, WRITE 992MB vs 201MB
//     unique, FETCH 1.35GB: partial-line scalar stores -> RFO + partial
//     writebacks + L2 write-allocate pressure evicting the weight stream).
//  - restore per-wave LDS-transpose epilogue: 128B full-line bf16x8 stores.
//    Swizzled [16][64] per-wave buffer (+16KB -> exactly 80KB LDS, 2 blk/CU).
//  - keep R2 wins: packed fragment-order weights (dense 1KB wave loads),
//    512-thr / 8-wave blocks, 16 waves/CU.
//  - restore 1-deep weight prefetch (bnx) in both GEMMs.
//
// Workspace: q[n][h][l][d] 67MB (o overwrites in-place) | k 67MB | v 67MB |
//            w1p bf16 1.5MB | w2p bf16 0.5MB.  Total ~203 MB.

typedef __bf16 bf16;
typedef __attribute__((ext_vector_type(8))) __bf16 bf16x8;
typedef __attribute__((ext_vector_type(4))) __bf16 bf16x4;
typedef __attribute__((ext_vector_type(4))) float f32x4;

#define MFMA16(A, B, C) __builtin_amdgcn_mfma_f32_16x16x32_bf16((A), (B), (C), 0, 0, 0)

__device__ __forceinline__ float fast_exp2(float x) { return __builtin_amdgcn_exp2f(x); }

// XOR-swizzled A-tile element index: rows x 512 cols bf16, unpadded.
// granule (16B) index = (c>>3) ^ (n>>4 & 7) ^ (n & 7): spreads both the
// n-strided staging writes and the b128 frag reads.
__device__ __forceinline__ int aswz(int n, int c) {
  int g = (c >> 3) ^ ((n >> 4) & 7) ^ (n & 7);
  return n * 512 + (g << 3) + (c & 7);
}

// Epilogue buffer swizzle: [16 rows][64 cols] bf16, granule-XOR by row.
// read back as b128: lane reads granule (lane&7)^row(&7) -> bank-optimal.
__device__ __forceinline__ int eswz(int row, int col) {
  return row * 64 + ((((col >> 3) ^ (row & 7))) << 3) + (col & 7);
}

// ---------------------------------------------------------------- cvt + pack
// Pack weights into per-wave fragment order:
//   wp[((t*16 + ks)*64 + lane)*8 + e] = wf[t*16 + (lane&15)][ks*32 + (lane>>4)*8 + e]
// so a wave's (tile t, kslice ks) load is one contiguous 1KB block.
// w1: 96 tiles (1536 couts), w2: 32 tiles (512 couts). 1 thread per (t,ks,lane).
__global__ void cvt_pack(const float* __restrict__ w1f, const float* __restrict__ w2f,
                         bf16* __restrict__ w1p, bf16* __restrict__ w2p) {
  int i = blockIdx.x * 256 + threadIdx.x;   // 0..131071
  const float* src;
  bf16* dst;
  if (i < 98304) { src = w1f; dst = w1p; }
  else           { src = w2f; dst = w2p; i -= 98304; }
  int lane = i & 63;
  int ks   = (i >> 6) & 15;
  int t    = i >> 10;
  int cout = t * 16 + (lane & 15);
  int c0   = ks * 32 + (lane >> 4) * 8;
  float4 a = *(const float4*)(src + (size_t)cout * 512 + c0);
  float4 b = *(const float4*)(src + (size_t)cout * 512 + c0 + 4);
  bf16x8 r;
  r[0] = (bf16)a.x; r[1] = (bf16)a.y; r[2] = (bf16)a.z; r[3] = (bf16)a.w;
  r[4] = (bf16)b.x; r[5] = (bf16)b.y; r[6] = (bf16)b.z; r[7] = (bf16)b.w;
  *(bf16x8*)(dst + (size_t)i * 8) = r;
}

// ---------------------------------------------------------------- QKV GEMM
// Block = 64 rows (window l, n-quarter) x K=512, A swizzled in 64KB LDS.
// 8 waves x 64 couts; 3 chunks of 512 couts = {q,k,v}; head hh == wave.
// Per wave per ks: 4 packed 1KB weight loads (1-deep prefetch) + 4 ds_read_b128
// + 16 MFMA. 2 blocks/CU, 16 waves/CU: TLP + prefetch hide L2 weight latency.
// Epilogue: per-wave swizzled LDS transpose -> 8x128B full-line stores.
__global__ void __launch_bounds__(512, 4) gemm_qkv(
    const float* __restrict__ x, const bf16* __restrict__ w1p,
    const float* __restrict__ b1,
    bf16* __restrict__ qo, bf16* __restrict__ ko, bf16* __restrict__ vo) {
  extern __shared__ bf16 Al[];              // 64*512 swizzled + epilogue buf
  bf16* Ep = Al + 64 * 512;                 // 8 waves x [16][64] swizzled
  const int tid = threadIdx.x;
  const int bm  = blockIdx.x;               // 0..1023
  const int l   = bm >> 2;
  const int n0  = (bm & 3) << 6;
  const int b   = l >> 4, ih = (l >> 2) & 3, iw = l & 3;
  const int h0  = ih * 16 + (n0 >> 4);      // 4 h-rows of the window
  const int w0  = iw * 16;

  // stage A: 64 n-rows x 512 c, fp32 gather -> bf16 swizzled LDS
  for (int j = 0; j < 16; ++j) {
    int f4  = j * 512 + tid;                // 0..8191
    int c   = f4 >> 4;                      // 16 float4 per channel
    int qq  = f4 & 15;
    int wsh = qq >> 2;                      // 0..3
    int w4  = (qq & 3) << 2;
    float4 xf = *(const float4*)(x + (((b * 512 + c) * 64 + h0 + wsh) * 64 + w0 + w4));
    int nb = wsh * 16 + w4;                 // 0..60
    Al[aswz(nb + 0, c)] = (bf16)xf.x;
    Al[aswz(nb + 1, c)] = (bf16)xf.y;
    Al[aswz(nb + 2, c)] = (bf16)xf.z;
    Al[aswz(nb + 3, c)] = (bf16)xf.w;
  }
  __syncthreads();

  const int wave = tid >> 6, lane = tid & 63;
  const int l15 = lane & 15, quad = lane >> 4;
  bf16* Epw = Ep + wave * 16 * 64;
  const f32x4 fz = {0.f, 0.f, 0.f, 0.f};

  for (int nc = 0; nc < 3; ++nc) {
    const int t0w = nc * 512 + wave * 64;   // cout base of this wave's chunk
    const int tb  = t0w >> 4;               // base 16-cout tile
    f32x4 acc[4][4];
#pragma unroll
    for (int a = 0; a < 4; ++a)
#pragma unroll
      for (int c2 = 0; c2 < 4; ++c2) acc[a][c2] = fz;

    bf16x8 bfr[4];
#pragma unroll
    for (int ct = 0; ct < 4; ++ct)
      bfr[ct] = *(const bf16x8*)&w1p[((size_t)((tb + ct) * 16 + 0) * 64 + lane) * 8];
#pragma unroll
    for (int ks = 0; ks < 16; ++ks) {
      bf16x8 bnx[4];
      if (ks < 15) {
#pragma unroll
        for (int ct = 0; ct < 4; ++ct)
          bnx[ct] = *(const bf16x8*)&w1p[((size_t)((tb + ct) * 16 + ks + 1) * 64 + lane) * 8];
      }
      bf16x8 af[4];
#pragma unroll
      for (int lt = 0; lt < 4; ++lt)
        af[lt] = *(const bf16x8*)&Al[aswz(lt * 16 + l15, ks * 32 + quad * 8)];
#pragma unroll
      for (int lt = 0; lt < 4; ++lt)
#pragma unroll
        for (int ct = 0; ct < 4; ++ct)
          acc[lt][ct] = MFMA16(af[lt], bfr[ct], acc[lt][ct]);
#pragma unroll
      for (int ct = 0; ct < 4; ++ct) bfr[ct] = bnx[ct];
    }

    // epilogue: per-wave swizzled LDS transpose -> 128B full-line stores
    bf16* dst = (nc == 0) ? qo : (nc == 1) ? ko : vo;
    const float scale = (nc == 0) ? 0.125f : 1.0f;
    const int hh = wave;                    // head index
    float bias[4];
#pragma unroll
    for (int ct = 0; ct < 4; ++ct) bias[ct] = b1[t0w + ct * 16 + l15];

    const int rr = lane >> 3, c8 = lane & 7;
#pragma unroll
    for (int lt = 0; lt < 4; ++lt) {
#pragma unroll
      for (int ct = 0; ct < 4; ++ct)
#pragma unroll
        for (int r = 0; r < 4; ++r)
          Epw[eswz(quad * 4 + r, ct * 16 + l15)] =
              (bf16)((acc[lt][ct][r] + bias[ct]) * scale);
#pragma unroll
      for (int half = 0; half < 2; ++half) {
        int row = half * 8 + rr;
        bf16x8 vv = *(const bf16x8*)&Epw[row * 64 + ((c8 ^ rr) << 3)];
        int n = n0 + lt * 16 + row;
        *(bf16x8*)&dst[((size_t)(n * 8 + hh) * 256 + l) * 64 + c8 * 8] = vv;
      }
    }
  }
}

// ---------------------------------------------------------------- attention
// One block per (n,h). K LDS [256][72], V^T LDS [64][264], per-wave P [16][264].
// Output overwrites q in-place; writes via per-wave transpose -> 128B chunks.
__global__ void __launch_bounds__(512, 2) attn_win(
    bf16* __restrict__ qio, const bf16* __restrict__ kg, const bf16* __restrict__ vg) {
  extern __shared__ bf16 sm[];
  bf16* Kl = sm;
  bf16* Vt = sm + 256 * 72;
  bf16* Pl = Vt + 64 * 264;
  const int tid = threadIdx.x;
  const int bb = blockIdx.x;
  const int n = bb >> 3, h = bb & 7;
  const size_t base = (size_t)(n * 8 + h) * 16384;
  const bf16* Kg = kg + base;
  const bf16* Vg = vg + base;
  bf16* Qg = qio + base;

  for (int j = 0; j < 4; ++j) {
    int cc = j * 512 + tid;
    int m = cc >> 3, dc = cc & 7;
    bf16x8 t = *(const bf16x8*)(Kg + m * 64 + dc * 8);
    *(bf16x8*)&Kl[m * 72 + dc * 8] = t;
  }
  for (int j = 0; j < 4; ++j) {
    int cc = j * 512 + tid;
    int dc = cc >> 8, m = cc & 255;
    bf16x8 t = *(const bf16x8*)(Vg + m * 64 + dc * 8);
#pragma unroll
    for (int s = 0; s < 8; ++s) Vt[(dc * 8 + s) * 264 + m] = t[s];
  }

  const int wave = tid >> 6, lane = tid & 63;
  const int l15 = lane & 15, quad = lane >> 4;
  const int lb = wave * 32;
  bf16* Pw = Pl + wave * 16 * 264;

  bf16x8 qf[2][2];
#pragma unroll
  for (int lt = 0; lt < 2; ++lt)
#pragma unroll
    for (int ks = 0; ks < 2; ++ks)
      qf[lt][ks] = *(const bf16x8*)(Qg + (lb + lt * 16 + l15) * 64 + ks * 32 + quad * 8);

  __syncthreads();

  const f32x4 fz = {0.f, 0.f, 0.f, 0.f};
  const float LOG2E = 1.44269504088896340736f;
  for (int lt = 0; lt < 2; ++lt) {
    f32x4 s[16];
#pragma unroll
    for (int mt = 0; mt < 16; ++mt) s[mt] = fz;
#pragma unroll
    for (int mt = 0; mt < 16; ++mt)
#pragma unroll
      for (int ks = 0; ks < 2; ++ks) {
        bf16x8 kf = *(const bf16x8*)&Kl[(mt * 16 + l15) * 72 + ks * 32 + quad * 8];
        s[mt] = MFMA16(qf[lt][ks], kf, s[mt]);
      }
    float rmax[4], rsum[4];
#pragma unroll
    for (int r = 0; r < 4; ++r) {
      float mx = s[0][r];
#pragma unroll
      for (int mt = 1; mt < 16; ++mt) mx = fmaxf(mx, s[mt][r]);
#pragma unroll
      for (int xo = 1; xo < 16; xo <<= 1) mx = fmaxf(mx, __shfl_xor(mx, xo, 16));
      rmax[r] = mx;
      rsum[r] = 0.f;
    }
#pragma unroll
    for (int mt = 0; mt < 16; ++mt) {
#pragma unroll
      for (int r = 0; r < 4; ++r) {
        float p = fast_exp2((s[mt][r] - rmax[r]) * LOG2E);
        bf16 pb = (bf16)p;
        rsum[r] += (float)pb;
        Pw[(quad * 4 + r) * 264 + mt * 16 + l15] = pb;
      }
    }
#pragma unroll
    for (int r = 0; r < 4; ++r)
#pragma unroll
      for (int xo = 1; xo < 16; xo <<= 1) rsum[r] += __shfl_xor(rsum[r], xo, 16);

    bf16x8 pf[8];
#pragma unroll
    for (int mk = 0; mk < 8; ++mk)
      pf[mk] = *(const bf16x8*)&Pw[l15 * 264 + mk * 32 + quad * 8];
    f32x4 of[4];
#pragma unroll
    for (int dt = 0; dt < 4; ++dt) of[dt] = fz;
#pragma unroll
    for (int dt = 0; dt < 4; ++dt)
#pragma unroll
      for (int mk = 0; mk < 8; ++mk) {
        bf16x8 vf = *(const bf16x8*)&Vt[(dt * 16 + l15) * 264 + mk * 32 + quad * 8];
        of[dt] = MFMA16(pf[mk], vf, of[dt]);
      }
    float inv[4];
#pragma unroll
    for (int r = 0; r < 4; ++r) inv[r] = 1.0f / rsum[r];

    // o-write: per-wave transpose (reuse Pw) -> 128B contiguous bf16x8 stores
    bf16* Ew = Pw;  // [16][72] region
#pragma unroll
    for (int dt = 0; dt < 4; ++dt)
#pragma unroll
      for (int r = 0; r < 4; ++r)
        Ew[(quad * 4 + r) * 72 + dt * 16 + l15] = (bf16)(of[dt][r] * inv[r]);
    const int rr = lane >> 3, ch8 = (lane & 7) * 8;
#pragma unroll
    for (int half = 0; half < 2; ++half) {
      int row = half * 8 + rr;
      bf16x8 vv = *(const bf16x8*)&Ew[row * 72 + ch8];
      *(bf16x8*)(Qg + (lb + lt * 16 + row) * 64 + ch8) = vv;
    }
  }
}

// ---------------------------------------------------------------- out proj
// Swapped MFMA operands: D = W2 x O^T, C-layout row=cout col=n, so stores are
// full 64B fp32 lines along w. 512-thr blocks, 8 waves x 64 couts = all 512.
__global__ void __launch_bounds__(512, 4) gemm_out(
    const bf16* __restrict__ og, const bf16* __restrict__ w2p,
    const float* __restrict__ b2, float* __restrict__ out) {
  extern __shared__ bf16 Al[];  // 64*512 swizzled
  const int tid = threadIdx.x;
  const int bm = blockIdx.x;    // 0..1023
  const int l = bm >> 2;
  const int n0 = (bm & 3) << 6;
  const int b = l >> 4, ih = (l >> 2) & 3, iw = l & 3;

  for (int j = 0; j < 8; ++j) {  // o[n][h][l][d] gather -> swizzled LDS rows
    int cc = j * 512 + tid;      // 0..4095
    int nl = cc >> 6;            // 0..63
    int ch = cc & 63;
    int hh = ch >> 3, d8 = (ch & 7) * 8;
    bf16x8 t = *(const bf16x8*)(og + ((size_t)((n0 + nl) * 8 + hh) * 256 + l) * 64 + d8);
    *(bf16x8*)&Al[aswz(nl, ch * 8)] = t;
  }
  __syncthreads();

  const int wave = tid >> 6, lane = tid & 63;
  const int l15 = lane & 15, quad = lane >> 4;
  const int t0w = wave * 64;     // this wave's 64 couts (512 total)
  const int tb  = wave * 4;
  const f32x4 fz = {0.f, 0.f, 0.f, 0.f};

  f32x4 acc[4][4];
#pragma unroll
  for (int a = 0; a < 4; ++a)
#pragma unroll
    for (int c2 = 0; c2 < 4; ++c2) acc[a][c2] = fz;

  bf16x8 bfr[4];
#pragma unroll
  for (int ct = 0; ct < 4; ++ct)
    bfr[ct] = *(const bf16x8*)&w2p[((size_t)((tb + ct) * 16 + 0) * 64 + lane) * 8];
#pragma unroll
  for (int ks = 0; ks < 16; ++ks) {
    bf16x8 bnx[4];
    if (ks < 15) {
#pragma unroll
      for (int ct = 0; ct < 4; ++ct)
        bnx[ct] = *(const bf16x8*)&w2p[((size_t)((tb + ct) * 16 + ks + 1) * 64 + lane) * 8];
    }
    bf16x8 af[4];
#pragma unroll
    for (int lt = 0; lt < 4; ++lt)
      af[lt] = *(const bf16x8*)&Al[aswz(lt * 16 + l15, ks * 32 + quad * 8)];
#pragma unroll
    for (int lt = 0; lt < 4; ++lt)
#pragma unroll
      for (int ct = 0; ct < 4; ++ct)
        acc[lt][ct] = MFMA16(bfr[ct], af[lt], acc[lt][ct]);  // swapped: rows=cout
#pragma unroll
    for (int ct = 0; ct < 4; ++ct) bfr[ct] = bnx[ct];
  }

#pragma unroll
  for (int ct = 0; ct < 4; ++ct) {
    float4 bias4 = *(const float4*)&b2[t0w + ct * 16 + quad * 4];
#pragma unroll
    for (int lt = 0; lt < 4; ++lt) {
      const int nbase = n0 + lt * 16;       // mult of 16 -> wsh uniform
      const int wsh = nbase >> 4;
      size_t rowbase = (((size_t)b * 512) * 64 + (size_t)ih * 16 + wsh) * 64 + iw * 16 + l15;
#pragma unroll
      for (int r = 0; r < 4; ++r) {
        int cout = t0w + ct * 16 + quad * 4 + r;
        out[rowbase + (size_t)cout * 4096] = acc[lt][ct][r] + ((const float*)&bias4)[r];
      }
    }
  }
}

// ---------------------------------------------------------------- launch
extern "C" void kernel_launch(void* const* d_in, const int* in_sizes, int n_in,
                              void* d_out, int out_size, void* d_ws, size_t ws_size,
                              hipStream_t stream) {
  (void)in_sizes; (void)n_in; (void)out_size; (void)ws_size;
  const float* x   = (const float*)d_in[0];
  const float* w1f = (const float*)d_in[1];
  const float* b1  = (const float*)d_in[2];
  const float* w2f = (const float*)d_in[3];
  const float* b2  = (const float*)d_in[4];
  float* out = (float*)d_out;

  char* ws = (char*)d_ws;
  bf16* q   = (bf16*)(ws);
  bf16* k   = (bf16*)(ws + 67108864ull);
  bf16* v   = (bf16*)(ws + 134217728ull);
  bf16* w1p = (bf16*)(ws + 201326592ull);
  bf16* w2p = (bf16*)(ws + 201326592ull + 1572864ull);

  const int LDS_QKV  = (64 * 512 + 8 * 16 * 64) * 2;              //  81,920 B
  const int LDS_ATTN = (256 * 72 + 64 * 264 + 8 * 16 * 264) * 2;  // 138,240 B
  const int LDS_OUT  = 64 * 512 * 2;                              //  65,536 B
  hipFuncSetAttribute(reinterpret_cast<const void*>(gemm_qkv),
                      hipFuncAttributeMaxDynamicSharedMemorySize, LDS_QKV);
  hipFuncSetAttribute(reinterpret_cast<const void*>(attn_win),
                      hipFuncAttributeMaxDynamicSharedMemorySize, LDS_ATTN);
  hipFuncSetAttribute(reinterpret_cast<const void*>(gemm_out),
                      hipFuncAttributeMaxDynamicSharedMemorySize, LDS_OUT);

  hipLaunchKernelGGL(cvt_pack, dim3(512), dim3(256), 0, stream, w1f, w2f, w1p, w2p);
  hipLaunchKernelGGL(gemm_qkv, dim3(1024), dim3(512), LDS_QKV, stream, x, w1p, b1, q, k, v);
  hipLaunchKernelGGL(attn_win, dim3(2048), dim3(512), LDS_ATTN, stream, q, k, v);
  hipLaunchKernelGGL(gemm_out, dim3(1024), dim3(512), LDS_OUT, stream, q, w2p, b2, out);
}